// Round 6
// baseline (254.181 us; speedup 1.0000x reference)
//
#include <hip/hip_runtime.h>
#include <math.h>

#define BB 16
#define NN 2048
#define DD 1024
#define KH 15
#define KL 5
#define NH 240      // BB*KH
#define NBANK 320   // BB*(KH+KL)

// ws layout (4-byte words):
#define WS_BAGMAX 0     // float[16] (each holds global max; finalize takes max)
#define WS_BAGSUM 32    // float[16] per-bag score sums
#define WS_DONE   48    // int, block-done counter for fused finalize
#define WS_SELH   64    // int[240]
#define WS_SELL   320   // int[80]
#define WS_PNUM   512   // float[1280]: pnum[q*4+quarter]
#define WS_PDEN   1792  // float[1280]

// ---- fused stats + selection: 16 blocks x 256 ----
// key = (score_bits<<32)|idx reproduces jnp stable argsort order (scores >= 0).
// All per-thread arrays fully unrolled -> VGPRs (no scratch; round-3 lesson).
__global__ void __launch_bounds__(256) k_select(const float* __restrict__ score,
                                                float* __restrict__ ws,
                                                int* __restrict__ selH,
                                                int* __restrict__ selL) {
    const unsigned long long INV = ~0ULL;
    int b = blockIdx.x, t = threadIdx.x;
    int w = t >> 6, l = t & 63;
    if (b == 0 && t == 0) ((int*)ws)[WS_DONE] = 0;   // re-init (ws poisoned each call)

    // own-bag keys (8 per thread, register-resident)
    const float* sc = score + b * NN;
    unsigned long long key[8];
    float sv[8];
    bool alive[8];
    float sm = 0.f;
    #pragma unroll
    for (int j = 0; j < 8; ++j) {
        int i = t + 256 * j;
        float s = sc[i];
        sv[j] = s;
        sm += s;
        key[j] = ((unsigned long long)__float_as_uint(s) << 32) | (unsigned)i;
    }
    // global max/min scan over all bags (coalesced, L2-resident)
    float gmx = -1e30f, gmn = 1e30f;
    for (int i = t; i < BB * NN; i += 256) {
        float s = score[i];
        gmx = fmaxf(gmx, s); gmn = fminf(gmn, s);
    }
    __shared__ float rmx[256], rmn[256], rsm[256];
    rmx[t] = gmx; rmn[t] = gmn; rsm[t] = sm;
    __syncthreads();
    for (int s2 = 128; s2 > 0; s2 >>= 1) {
        if (t < s2) {
            rmx[t] = fmaxf(rmx[t], rmx[t + s2]);
            rmn[t] = fminf(rmn[t], rmn[t + s2]);
            rsm[t] += rsm[t + s2];
        }
        __syncthreads();
    }
    float sgmax = rmx[0], sgmin = rmn[0];
    if (t == 0) {
        ws[WS_BAGMAX + b] = sgmax;     // same value every block; finalize maxes them
        ws[WS_BAGSUM + b] = rsm[0];    // own-bag sum
    }
    __shared__ unsigned long long wmin[4];

    // ---- H band: extract 15 smallest with score >= gmax-0.3 ----
    float hlo = sgmax - 0.3f;
    #pragma unroll
    for (int j = 0; j < 8; ++j) alive[j] = (sv[j] >= hlo);
    int r = 0;
    for (; r < KH; ++r) {
        unsigned long long v = INV;
        #pragma unroll
        for (int j = 0; j < 8; ++j) if (alive[j] && key[j] < v) v = key[j];
        #pragma unroll
        for (int s2 = 32; s2 > 0; s2 >>= 1) {
            unsigned long long o = __shfl_xor(v, s2);
            if (o < v) v = o;
        }
        if (l == 0) wmin[w] = v;
        __syncthreads();
        unsigned long long win = wmin[0];
        #pragma unroll
        for (int ww = 1; ww < 4; ++ww) if (wmin[ww] < win) win = wmin[ww];
        __syncthreads();                       // wmin reused next round
        if (win == INV) break;                 // uniform across block
        if (t == 0) selH[b * KH + r] = (int)(win & 0xffffffffu);
        #pragma unroll
        for (int j = 0; j < 8; ++j) alive[j] = alive[j] && (key[j] != win);
    }
    if (t == 0) for (int k = r; k < KH; ++k) selH[b * KH + k] = -1;

    // ---- L band: even ranks among [gmin, gmin+1e-9] (typically 0-1 elements) ----
    float llo = sgmin, lhi = sgmin + 1e-9f;
    #pragma unroll
    for (int j = 0; j < 8; ++j) alive[j] = (sv[j] >= llo && sv[j] <= lhi);
    int nsel = 0;
    for (int rr = 0; rr < 2 * KL; ++rr) {
        unsigned long long v = INV;
        #pragma unroll
        for (int j = 0; j < 8; ++j) if (alive[j] && key[j] < v) v = key[j];
        #pragma unroll
        for (int s2 = 32; s2 > 0; s2 >>= 1) {
            unsigned long long o = __shfl_xor(v, s2);
            if (o < v) v = o;
        }
        if (l == 0) wmin[w] = v;
        __syncthreads();
        unsigned long long win = wmin[0];
        #pragma unroll
        for (int ww = 1; ww < 4; ++ww) if (wmin[ww] < win) win = wmin[ww];
        __syncthreads();
        if (win == INV) break;
        if ((rr & 1) == 0) {
            if (t == 0) selL[b * KL + (rr >> 1)] = (int)(win & 0xffffffffu);
            nsel++;
        }
        #pragma unroll
        for (int j = 0; j < 8; ++j) alive[j] = alive[j] && (key[j] != win);
    }
    if (t == 0) for (int k = nsel; k < KL; ++k) selL[b * KL + k] = -1;
}

// ---- Gram partials + fused finalize: 320 blocks (80 q-quads x 4 n-quarters) ----
__global__ void __launch_bounds__(256) k_gram(const float* __restrict__ fea,
                                              const int* __restrict__ selH,
                                              const int* __restrict__ selL,
                                              const int* __restrict__ label,
                                              const float* __restrict__ t_logit,
                                              const float* __restrict__ ori,
                                              const float* __restrict__ l2w,
                                              float* __restrict__ ws,
                                              float* __restrict__ out) {
    int blk = blockIdx.x, t = threadIdx.x;
    int g = blk >> 2, h = blk & 3;
    int q0 = g * 4;
    __shared__ int s_row[NBANK], s_lab[NBANK];
    __shared__ int s_qrow[4], s_qt[4];
    for (int n = t; n < NBANK; n += 256) {
        int bn, in_, ln;
        if (n < NH) { bn = n / KH; in_ = selH[n]; ln = label[bn]; }
        else        { bn = (n - NH) / KL; in_ = selL[n - NH]; ln = 2; }
        s_row[n] = (in_ >= 0) ? bn * NN + in_ : -1;
        s_lab[n] = ln;
    }
    if (t < 4) {
        int q = q0 + t; int bq, iq, qt;
        if (q < NH) { bq = q / KH; iq = selH[q]; qt = label[bq]; }
        else        { bq = (q - NH) / KL; iq = selL[q - NH]; qt = 2; }
        s_qrow[t] = (iq >= 0) ? bq * NN + iq : 0;   // fallback row; masked in finalize
        s_qt[t] = qt;
    }
    __syncthreads();
    int w = t >> 6, l = t & 63;
    const float4* qp0 = (const float4*)(fea + (size_t)s_qrow[0] * DD);
    const float4* qp1 = (const float4*)(fea + (size_t)s_qrow[1] * DD);
    const float4* qp2 = (const float4*)(fea + (size_t)s_qrow[2] * DD);
    const float4* qp3 = (const float4*)(fea + (size_t)s_qrow[3] * DD);
    int qt0 = s_qt[0], qt1 = s_qt[1], qt2 = s_qt[2], qt3 = s_qt[3];
    float d0 = 0, d1 = 0, d2 = 0, d3 = 0;
    float n0 = 0, n1 = 0, n2 = 0, n3 = 0;
    for (int k = 0; k < 20; ++k) {               // wave w: n in [h*80 + w*20, +20)
        int n = h * 80 + w * 20 + k;
        int rn = s_row[n];
        if (rn < 0) continue;                    // wave-uniform branch
        const float4* np_ = (const float4*)(fea + (size_t)rn * DD);
        float a0 = 0, a1 = 0, a2 = 0, a3 = 0;
        #pragma unroll
        for (int c = 0; c < 4; ++c) {
            float4 nv = np_[c * 64 + l];         // coalesced: 64 lanes x 16B contiguous
            float4 v;
            v = qp0[c * 64 + l]; a0 += nv.x * v.x + nv.y * v.y + nv.z * v.z + nv.w * v.w;
            v = qp1[c * 64 + l]; a1 += nv.x * v.x + nv.y * v.y + nv.z * v.z + nv.w * v.w;
            v = qp2[c * 64 + l]; a2 += nv.x * v.x + nv.y * v.y + nv.z * v.z + nv.w * v.w;
            v = qp3[c * 64 + l]; a3 += nv.x * v.x + nv.y * v.y + nv.z * v.z + nv.w * v.w;
        }
        #pragma unroll
        for (int s2 = 32; s2 > 0; s2 >>= 1) {    // butterfly: all lanes get full dot
            a0 += __shfl_xor(a0, s2);
            a1 += __shfl_xor(a1, s2);
            a2 += __shfl_xor(a2, s2);
            a3 += __shfl_xor(a3, s2);
        }
        int ln = s_lab[n];
        float e;
        e = __expf(a0 * 0.0625f); d0 += e; if (ln == qt0) n0 += e;
        e = __expf(a1 * 0.0625f); d1 += e; if (ln == qt1) n1 += e;
        e = __expf(a2 * 0.0625f); d2 += e; if (ln == qt2) n2 += e;
        e = __expf(a3 * 0.0625f); d3 += e; if (ln == qt3) n3 += e;
    }
    __shared__ float s_pn[4][4], s_pd[4][4];     // [wave][q]
    if (l == 0) {
        s_pn[w][0] = n0; s_pn[w][1] = n1; s_pn[w][2] = n2; s_pn[w][3] = n3;
        s_pd[w][0] = d0; s_pd[w][1] = d1; s_pd[w][2] = d2; s_pd[w][3] = d3;
    }
    __syncthreads();
    if (t < 4) {
        float num = 0, den = 0;
        for (int ww = 0; ww < 4; ++ww) { num += s_pn[ww][t]; den += s_pd[ww][t]; }
        ws[WS_PNUM + (q0 + t) * 4 + h] = num;
        ws[WS_PDEN + (q0 + t) * 4 + h] = den;
    }

    // ---- last-block-done fused finalize ----
    __shared__ int s_old;
    __threadfence();                              // release partial writes (device scope)
    if (t == 0) s_old = atomicAdd((int*)ws + WS_DONE, 1);
    __syncthreads();
    if (s_old != 320 - 1) return;
    __threadfence();                              // acquire: see all blocks' partials

    __shared__ float sper[NBANK], sval[NBANK];
    __shared__ float sc16[16], sce[16];
    for (int q = t; q < NBANK; q += 256) {
        float num = 0, den = 0;
        #pragma unroll
        for (int hh = 0; hh < 4; ++hh) {
            num += ws[WS_PNUM + q * 4 + hh];
            den += ws[WS_PDEN + q * 4 + hh];
        }
        bool valid = (q < NH) ? (selH[q] >= 0) : (selL[q - NH] >= 0);
        sper[q] = valid ? (logf(den) - logf(num)) : 0.f;
        sval[q] = valid ? 1.f : 0.f;
    }
    __syncthreads();
    if (t < 16) {
        float s = 0, c = 0;
        for (int k = 0; k < KH; ++k) { s += sper[t * KH + k]; c += sval[t * KH + k]; }
        for (int k = 0; k < KL; ++k) { int q = NH + t * KL + k; s += sper[q]; c += sval[q]; }
        sc16[t] = s / c;
    } else if (t >= 64 && t < 80) {
        int b = t - 64;
        sce[b] = logf(expf(ori[2 * b]) + expf(ori[2 * b + 1])) - t_logit[0];
    }
    __syncthreads();
    if (t == 0) {
        float contrast = 0, ce = 0;
        for (int b = 0; b < 16; ++b) { contrast += sc16[b]; ce += sce[b]; }
        contrast *= (1.f / 16.f); ce *= (1.f / 16.f);
        float gmax = -1e30f, ssum = 0.f;
        for (int i = 0; i < 16; ++i) {
            gmax = fmaxf(gmax, ws[WS_BAGMAX + i]);
            ssum += ws[WS_BAGSUM + i];
        }
        float Dm = (ssum / (float)(BB * NN)) / gmax;
        float l2 = 1e-4f * (1.f - Dm) * (1.f - Dm) * l2w[0];
        out[0] = contrast + ce + l2;
    }
}

extern "C" void kernel_launch(void* const* d_in, const int* in_sizes, int n_in,
                              void* d_out, int out_size, void* d_ws, size_t ws_size,
                              hipStream_t stream) {
    const float* fea     = (const float*)d_in[0];
    const float* score   = (const float*)d_in[1];
    const int*   label   = (const int*)d_in[2];
    const float* t_logit = (const float*)d_in[3];
    const float* ori     = (const float*)d_in[4];
    const float* l2_wei  = (const float*)d_in[5];
    float* ws  = (float*)d_ws;
    int* selH  = (int*)d_ws + WS_SELH;
    int* selL  = (int*)d_ws + WS_SELL;
    float* out = (float*)d_out;

    hipLaunchKernelGGL(k_select, dim3(BB),  dim3(256), 0, stream, score, ws, selH, selL);
    hipLaunchKernelGGL(k_gram,   dim3(320), dim3(256), 0, stream, fea, selH, selL, label,
                       t_logit, ori, l2_wei, ws, out);
}

// Round 7
// 231.848 us; speedup vs baseline: 1.0963x; 1.0963x over previous
//
#include <hip/hip_runtime.h>
#include <math.h>

#define BB 16
#define NN 2048
#define DD 1024
#define KH 15
#define KL 5
#define NH 240      // BB*KH
#define NBANK 320   // BB*(KH+KL)

// ws layout (4-byte words):
#define WS_BAGMAX 0     // float[16]
#define WS_BAGMIN 16    // float[16]
#define WS_BAGSUM 32    // float[16]
#define WS_DONE   48    // int, block-done counter for fused finalize
#define WS_SELH   64    // int[240]
#define WS_SELL   320   // int[80]
#define WS_PNUM   512   // float[1280]: pnum[q*4+quarter]
#define WS_PDEN   1792  // float[1280]

// ---------------- per-bag stats: 16 blocks x 256 ----------------
__global__ void k_stats(const float* __restrict__ score, float* __restrict__ ws) {
    int b = blockIdx.x, t = threadIdx.x;
    if (b == 0 && t == 0) ((int*)ws)[WS_DONE] = 0;   // re-init (ws poisoned each call)
    const float* sc = score + b * NN;
    float mx = -1e30f, mn = 1e30f, sm = 0.f;
    for (int j = t; j < NN; j += 256) {
        float s = sc[j];
        mx = fmaxf(mx, s); mn = fminf(mn, s); sm += s;
    }
    __shared__ float rmx[256], rmn[256], rsm[256];
    rmx[t] = mx; rmn[t] = mn; rsm[t] = sm;
    __syncthreads();
    for (int s2 = 128; s2 > 0; s2 >>= 1) {
        if (t < s2) {
            rmx[t] = fmaxf(rmx[t], rmx[t + s2]);
            rmn[t] = fminf(rmn[t], rmn[t + s2]);
            rsm[t] += rsm[t + s2];
        }
        __syncthreads();
    }
    if (t == 0) {
        ws[WS_BAGMAX + b] = rmx[0];
        ws[WS_BAGMIN + b] = rmn[0];
        ws[WS_BAGSUM + b] = rsm[0];
    }
}

// ---- selection via serial min-extraction (wave butterfly): 16 blocks x 256 ----
// key = (score_bits<<32)|idx reproduces jnp stable argsort order (scores >= 0).
// All per-thread arrays fully unrolled -> VGPRs (no scratch; round-3 lesson).
__global__ void __launch_bounds__(256) k_select(const float* __restrict__ score,
                                                const float* __restrict__ ws,
                                                int* __restrict__ selH,
                                                int* __restrict__ selL) {
    const unsigned long long INV = ~0ULL;
    int b = blockIdx.x, t = threadIdx.x;
    int w = t >> 6, l = t & 63;
    __shared__ float sgmax, sgmin;
    __shared__ unsigned long long wmin[4];
    if (t == 0) {
        float mx = -1e30f, mn = 1e30f;
        for (int i = 0; i < BB; ++i) {
            mx = fmaxf(mx, ws[WS_BAGMAX + i]);
            mn = fminf(mn, ws[WS_BAGMIN + i]);
        }
        sgmax = mx; sgmin = mn;
    }
    __syncthreads();
    const float* sc = score + b * NN;
    unsigned long long key[8];
    float sv[8];
    bool alive[8];
    #pragma unroll
    for (int j = 0; j < 8; ++j) {
        int i = t + 256 * j;
        float s = sc[i];
        sv[j] = s;
        key[j] = ((unsigned long long)__float_as_uint(s) << 32) | (unsigned)i;
    }

    // ---- H band: extract 15 smallest with score >= gmax-0.3 ----
    float hlo = sgmax - 0.3f;
    #pragma unroll
    for (int j = 0; j < 8; ++j) alive[j] = (sv[j] >= hlo);
    int r = 0;
    for (; r < KH; ++r) {
        unsigned long long v = INV;
        #pragma unroll
        for (int j = 0; j < 8; ++j) if (alive[j] && key[j] < v) v = key[j];
        #pragma unroll
        for (int s2 = 32; s2 > 0; s2 >>= 1) {
            unsigned long long o = __shfl_xor(v, s2);
            if (o < v) v = o;
        }
        if (l == 0) wmin[w] = v;
        __syncthreads();
        unsigned long long win = wmin[0];
        #pragma unroll
        for (int ww = 1; ww < 4; ++ww) if (wmin[ww] < win) win = wmin[ww];
        __syncthreads();                       // wmin reused next round
        if (win == INV) break;                 // uniform across block
        if (t == 0) selH[b * KH + r] = (int)(win & 0xffffffffu);
        #pragma unroll
        for (int j = 0; j < 8; ++j) alive[j] = alive[j] && (key[j] != win);
    }
    if (t == 0) for (int k = r; k < KH; ++k) selH[b * KH + k] = -1;

    // ---- L band: even ranks among [gmin, gmin+1e-9] (typically 0-1 elements) ----
    float llo = sgmin, lhi = sgmin + 1e-9f;
    #pragma unroll
    for (int j = 0; j < 8; ++j) alive[j] = (sv[j] >= llo && sv[j] <= lhi);
    int nsel = 0;
    for (int rr = 0; rr < 2 * KL; ++rr) {
        unsigned long long v = INV;
        #pragma unroll
        for (int j = 0; j < 8; ++j) if (alive[j] && key[j] < v) v = key[j];
        #pragma unroll
        for (int s2 = 32; s2 > 0; s2 >>= 1) {
            unsigned long long o = __shfl_xor(v, s2);
            if (o < v) v = o;
        }
        if (l == 0) wmin[w] = v;
        __syncthreads();
        unsigned long long win = wmin[0];
        #pragma unroll
        for (int ww = 1; ww < 4; ++ww) if (wmin[ww] < win) win = wmin[ww];
        __syncthreads();
        if (win == INV) break;
        if ((rr & 1) == 0) {
            if (t == 0) selL[b * KL + (rr >> 1)] = (int)(win & 0xffffffffu);
            nsel++;
        }
        #pragma unroll
        for (int j = 0; j < 8; ++j) alive[j] = alive[j] && (key[j] != win);
    }
    if (t == 0) for (int k = nsel; k < KL; ++k) selL[b * KL + k] = -1;
}

// ---- Gram partials + fused finalize: 320 blocks (80 q-quads x 4 n-quarters) ----
__global__ void __launch_bounds__(256) k_gram(const float* __restrict__ fea,
                                              const int* __restrict__ selH,
                                              const int* __restrict__ selL,
                                              const int* __restrict__ label,
                                              const float* __restrict__ t_logit,
                                              const float* __restrict__ ori,
                                              const float* __restrict__ l2w,
                                              float* __restrict__ ws,
                                              float* __restrict__ out) {
    int blk = blockIdx.x, t = threadIdx.x;
    int g = blk >> 2, h = blk & 3;
    int q0 = g * 4;
    __shared__ int s_row[NBANK], s_lab[NBANK];
    __shared__ int s_qrow[4], s_qt[4];
    for (int n = t; n < NBANK; n += 256) {
        int bn, in_, ln;
        if (n < NH) { bn = n / KH; in_ = selH[n]; ln = label[bn]; }
        else        { bn = (n - NH) / KL; in_ = selL[n - NH]; ln = 2; }
        s_row[n] = (in_ >= 0) ? bn * NN + in_ : -1;
        s_lab[n] = ln;
    }
    if (t < 4) {
        int q = q0 + t; int bq, iq, qt;
        if (q < NH) { bq = q / KH; iq = selH[q]; qt = label[bq]; }
        else        { bq = (q - NH) / KL; iq = selL[q - NH]; qt = 2; }
        s_qrow[t] = (iq >= 0) ? bq * NN + iq : 0;   // fallback row; masked in finalize
        s_qt[t] = qt;
    }
    __syncthreads();
    int w = t >> 6, l = t & 63;
    const float4* qp0 = (const float4*)(fea + (size_t)s_qrow[0] * DD);
    const float4* qp1 = (const float4*)(fea + (size_t)s_qrow[1] * DD);
    const float4* qp2 = (const float4*)(fea + (size_t)s_qrow[2] * DD);
    const float4* qp3 = (const float4*)(fea + (size_t)s_qrow[3] * DD);
    int qt0 = s_qt[0], qt1 = s_qt[1], qt2 = s_qt[2], qt3 = s_qt[3];
    float d0 = 0, d1 = 0, d2 = 0, d3 = 0;
    float n0 = 0, n1 = 0, n2 = 0, n3 = 0;
    for (int k = 0; k < 20; ++k) {               // wave w: n in [h*80 + w*20, +20)
        int n = h * 80 + w * 20 + k;
        int rn = s_row[n];
        if (rn < 0) continue;                    // wave-uniform branch
        const float4* np_ = (const float4*)(fea + (size_t)rn * DD);
        float a0 = 0, a1 = 0, a2 = 0, a3 = 0;
        #pragma unroll
        for (int c = 0; c < 4; ++c) {
            float4 nv = np_[c * 64 + l];         // coalesced: 64 lanes x 16B contiguous
            float4 v;
            v = qp0[c * 64 + l]; a0 += nv.x * v.x + nv.y * v.y + nv.z * v.z + nv.w * v.w;
            v = qp1[c * 64 + l]; a1 += nv.x * v.x + nv.y * v.y + nv.z * v.z + nv.w * v.w;
            v = qp2[c * 64 + l]; a2 += nv.x * v.x + nv.y * v.y + nv.z * v.z + nv.w * v.w;
            v = qp3[c * 64 + l]; a3 += nv.x * v.x + nv.y * v.y + nv.z * v.z + nv.w * v.w;
        }
        #pragma unroll
        for (int s2 = 32; s2 > 0; s2 >>= 1) {    // butterfly: all lanes get full dot
            a0 += __shfl_xor(a0, s2);
            a1 += __shfl_xor(a1, s2);
            a2 += __shfl_xor(a2, s2);
            a3 += __shfl_xor(a3, s2);
        }
        int ln = s_lab[n];
        float e;
        e = __expf(a0 * 0.0625f); d0 += e; if (ln == qt0) n0 += e;
        e = __expf(a1 * 0.0625f); d1 += e; if (ln == qt1) n1 += e;
        e = __expf(a2 * 0.0625f); d2 += e; if (ln == qt2) n2 += e;
        e = __expf(a3 * 0.0625f); d3 += e; if (ln == qt3) n3 += e;
    }
    __shared__ float s_pn[4][4], s_pd[4][4];     // [wave][q]
    if (l == 0) {
        s_pn[w][0] = n0; s_pn[w][1] = n1; s_pn[w][2] = n2; s_pn[w][3] = n3;
        s_pd[w][0] = d0; s_pd[w][1] = d1; s_pd[w][2] = d2; s_pd[w][3] = d3;
    }
    __syncthreads();
    if (t < 4) {
        float num = 0, den = 0;
        for (int ww = 0; ww < 4; ++ww) { num += s_pn[ww][t]; den += s_pd[ww][t]; }
        ws[WS_PNUM + (q0 + t) * 4 + h] = num;
        ws[WS_PDEN + (q0 + t) * 4 + h] = den;
    }

    // ---- last-block-done fused finalize ----
    __shared__ int s_old;
    __threadfence();                              // release partial writes (device scope)
    if (t == 0) s_old = atomicAdd((int*)ws + WS_DONE, 1);
    __syncthreads();
    if (s_old != 320 - 1) return;
    __threadfence();                              // acquire: see all blocks' partials

    __shared__ float sper[NBANK], sval[NBANK];
    __shared__ float sc16[16], sce[16];
    for (int q = t; q < NBANK; q += 256) {
        float num = 0, den = 0;
        #pragma unroll
        for (int hh = 0; hh < 4; ++hh) {
            num += ws[WS_PNUM + q * 4 + hh];
            den += ws[WS_PDEN + q * 4 + hh];
        }
        bool valid = (q < NH) ? (selH[q] >= 0) : (selL[q - NH] >= 0);
        sper[q] = valid ? (logf(den) - logf(num)) : 0.f;
        sval[q] = valid ? 1.f : 0.f;
    }
    __syncthreads();
    if (t < 16) {
        float s = 0, c = 0;
        for (int k = 0; k < KH; ++k) { s += sper[t * KH + k]; c += sval[t * KH + k]; }
        for (int k = 0; k < KL; ++k) { int q = NH + t * KL + k; s += sper[q]; c += sval[q]; }
        sc16[t] = s / c;
    } else if (t >= 64 && t < 80) {
        int b = t - 64;
        sce[b] = logf(expf(ori[2 * b]) + expf(ori[2 * b + 1])) - t_logit[0];
    }
    __syncthreads();
    if (t == 0) {
        float contrast = 0, ce = 0;
        for (int b = 0; b < 16; ++b) { contrast += sc16[b]; ce += sce[b]; }
        contrast *= (1.f / 16.f); ce *= (1.f / 16.f);
        float gmax = -1e30f, ssum = 0.f;
        for (int i = 0; i < 16; ++i) {
            gmax = fmaxf(gmax, ws[WS_BAGMAX + i]);
            ssum += ws[WS_BAGSUM + i];
        }
        float Dm = (ssum / (float)(BB * NN)) / gmax;
        float l2 = 1e-4f * (1.f - Dm) * (1.f - Dm) * l2w[0];
        out[0] = contrast + ce + l2;
    }
}

extern "C" void kernel_launch(void* const* d_in, const int* in_sizes, int n_in,
                              void* d_out, int out_size, void* d_ws, size_t ws_size,
                              hipStream_t stream) {
    const float* fea     = (const float*)d_in[0];
    const float* score   = (const float*)d_in[1];
    const int*   label   = (const int*)d_in[2];
    const float* t_logit = (const float*)d_in[3];
    const float* ori     = (const float*)d_in[4];
    const float* l2_wei  = (const float*)d_in[5];
    float* ws  = (float*)d_ws;
    int* selH  = (int*)d_ws + WS_SELH;
    int* selL  = (int*)d_ws + WS_SELL;
    float* out = (float*)d_out;

    hipLaunchKernelGGL(k_stats,  dim3(BB),  dim3(256), 0, stream, score, ws);
    hipLaunchKernelGGL(k_select, dim3(BB),  dim3(256), 0, stream, score, ws, selH, selL);
    hipLaunchKernelGGL(k_gram,   dim3(320), dim3(256), 0, stream, fea, selH, selL, label,
                       t_logit, ori, l2_wei, ws, out);
}